// Round 4
// baseline (6388.391 us; speedup 1.0000x reference)
//
#include <hip/hip_runtime.h>

// ============================================================================
// LSTM+attention+MLP forward, fp32 throughout. T-chunked pipeline with
// online-softmax attention so the workspace fits any reasonable ws_size.
// B=32, T=4096, conv 8->16 (k=4 SAME), LSTM1/2: 16->64, LSTM3/4: 128->128.
// Feature-axis flips fold into row-flips of Wx2 / Wx4.
// Scans: k-split threads, weights pre-transposed (contiguous per thread),
// amdgpu_waves_per_eu clamps so weights stay VGPR-resident (1 WG/CU anyway).
// ============================================================================

#define TFULL 4096
#define NB 32

// ---------- fast math helpers (f32, ~1e-7 rel) ----------
__device__ __forceinline__ float fexp2(float x){ return __builtin_amdgcn_exp2f(x); }
__device__ __forceinline__ float frcp(float x){ return __builtin_amdgcn_rcpf(x); }
__device__ __forceinline__ float sigf(float x){ return frcp(1.f + fexp2(-1.44269504f*x)); }
__device__ __forceinline__ float tanh_(float x){
    float e = fexp2(fminf(2.88539008f*x, 126.f));   // exp(2x), clamp avoids inf-inf
    return (e - 1.f) * frcp(e + 1.f);
}

// ---------- init persistent state ----------
__global__ __launch_bounds__(256) void k_init(float* __restrict__ st1,
        float* __restrict__ st2, float* __restrict__ am, float* __restrict__ al,
        float* __restrict__ acc){
    int i = blockIdx.x * 256 + threadIdx.x;       // grid 64 -> i < 16384
    if (i < 8192)  st1[i] = 0.f;
    if (i < 16384) st2[i] = 0.f;
    if (i < 8192)  acc[i] = 0.f;
    if (i < 32){ am[i] = -3.4e38f; al[i] = 0.f; }
}

// ---------- one-time weight packing ----------
// W34  [128][1024] = [Wx3 | flipRows(Wx4)], b34 [1024]
// WhT2 [l][col 512][k 128]   (transposed Wh3/Wh4)
// WhT1 [l][col 256][k 64]    (transposed Wh1/Wh2)
// WxT1 [l][col 256][r 16]    (transposed Wx1 / row-flipped Wx2)
// b12  [l][256]
__global__ __launch_bounds__(256) void k_pack(
        const float* __restrict__ Wx1, const float* __restrict__ Wh1, const float* __restrict__ b1,
        const float* __restrict__ Wx2, const float* __restrict__ Wh2, const float* __restrict__ b2,
        const float* __restrict__ Wx3, const float* __restrict__ Wh3, const float* __restrict__ b3,
        const float* __restrict__ Wx4, const float* __restrict__ Wh4, const float* __restrict__ b4,
        float* __restrict__ W34, float* __restrict__ b34, float* __restrict__ WhT2,
        float* __restrict__ WhT1, float* __restrict__ WxT1, float* __restrict__ b12){
    int i0 = blockIdx.x * 256 + threadIdx.x;
    int stride = gridDim.x * 256;
    for (int e = i0; e < 131072; e += stride){
        int k = e >> 10, n = e & 1023;
        W34[e] = (n < 512) ? Wx3[k*512 + n] : Wx4[(127 - k)*512 + (n - 512)];
    }
    for (int e = i0; e < 1024; e += stride) b34[e] = (e < 512) ? b3[e] : b4[e - 512];
    for (int e = i0; e < 131072; e += stride){
        int l = e >> 16, r = e & 65535, col = r >> 7, k = r & 127;
        WhT2[e] = (l ? Wh4 : Wh3)[k*512 + col];
    }
    for (int e = i0; e < 32768; e += stride){
        int l = e >> 14, r = e & 16383, col = r >> 6, k = r & 63;
        WhT1[e] = (l ? Wh2 : Wh1)[k*256 + col];
    }
    for (int e = i0; e < 8192; e += stride){
        int l = e >> 12, q = e & 4095, col = q >> 4, r = q & 15;
        WxT1[e] = l ? Wx2[(15 - r)*256 + col] : Wx1[r*256 + col];
    }
    for (int e = i0; e < 512; e += stride) b12[e] = (e < 256) ? b1[e] : b2[e - 256];
}

// ---------- conv1d chunk: rows [t0, t0+C) -> xcv[(b*C+trel)][16]
__global__ __launch_bounds__(256) void k_conv(const float* __restrict__ X,
        const float* __restrict__ W, const float* __restrict__ Bv,
        float* __restrict__ out, int t0, int lc){
    __shared__ float Ws[512];
    __shared__ float bs[16];
    int tid = threadIdx.x;
    Ws[tid] = W[tid]; Ws[tid + 256] = W[tid + 256];
    if (tid < 16) bs[tid] = Bv[tid];
    __syncthreads();
    int m = blockIdx.x * 256 + tid;               // b*C + trel
    int b = m >> lc, trel = m & ((1 << lc) - 1);
    int t = t0 + trel;
    float o[16];
    #pragma unroll
    for (int co = 0; co < 16; ++co) o[co] = bs[co];
    #pragma unroll
    for (int w = 0; w < 4; ++w){
        int tt = t + w - 1;
        if (tt >= 0 && tt < TFULL){
            const float* xr = X + ((size_t)(b << 12) + tt) * 8;
            #pragma unroll
            for (int ci = 0; ci < 8; ++ci){
                float v = xr[ci];
                #pragma unroll
                for (int co = 0; co < 16; ++co) o[co] += v * Ws[(w*8 + ci)*16 + co];
            }
        }
    }
    float* op = out + (size_t)m * 16;
    #pragma unroll
    for (int q = 0; q < 4; ++q)
        *(float4*)(op + q*4) = make_float4(o[q*4], o[q*4+1], o[q*4+2], o[q*4+3]);
}

// ---------- layer-1 scan chunk: LSTM1 (l=0) / LSTM2 (l=1, row-flipped Wx).
// One WG per (lstm, batch); 512 threads = (col 0..255, half 0..1).
// half0: bias + x(16) + h[0..31];  half1: h[32..63].
__global__ void __launch_bounds__(512)
__attribute__((amdgpu_waves_per_eu(2, 2)))
k_scan1(const float* __restrict__ x,
        const float* __restrict__ WxT1, const float* __restrict__ WhT1,
        const float* __restrict__ b12,
        float* __restrict__ cc, float* __restrict__ st1, int C){
    int l = blockIdx.x >> 5;
    int b = blockIdx.x & 31;
    int j = threadIdx.x;
    int col = j & 255;
    int half = j >> 8;
    float4 wx4[4], wh4[8];
    float bias = 0.f;
    if (half == 0){
        const float4* wp = (const float4*)(WxT1 + ((size_t)l*256 + col)*16);
        #pragma unroll
        for (int i = 0; i < 4; ++i) wx4[i] = wp[i];
        bias = b12[l*256 + col];
    } else {
        #pragma unroll
        for (int i = 0; i < 4; ++i) wx4[i] = make_float4(0.f, 0.f, 0.f, 0.f);
    }
    {
        const float4* wp = (const float4*)(WhT1 + ((size_t)l*256 + col)*64 + half*32);
        #pragma unroll
        for (int i = 0; i < 8; ++i) wh4[i] = wp[i];
    }

    __shared__ float xs[128 * 16];   // up-to-128-step input tile
    __shared__ float zp[512];        // [half][col]
    __shared__ float hbufs[64];
    float c = 0.f;
    int sidx = (l*32 + b)*64 + (j & 63);
    if (j < 64){ c = st1[sidx]; hbufs[j] = st1[4096 + sidx]; }
    __syncthreads();

    const float* xb = x + ((size_t)b * C) * 16;
    float* ccb = cc + ((size_t)b * C) * 128 + (l << 6);

    for (int t = 0; t < C; ++t){
        int s = t & 127;
        if (s == 0){
            __syncthreads();
            const float4* src = (const float4*)(xb + (size_t)t * 16);
            float4* dst = (float4*)xs;
            if (t + (j >> 2) < C) dst[j] = src[j];
            __syncthreads();
        }
        float a0 = bias, a1 = 0.f, a2 = 0.f, a3 = 0.f;
        if (half == 0){
            const float4* xr = (const float4*)(xs + s * 16);
            #pragma unroll
            for (int r4 = 0; r4 < 4; ++r4){
                float4 xv = xr[r4];
                a0 = fmaf(xv.x, wx4[r4].x, a0);
                a1 = fmaf(xv.y, wx4[r4].y, a1);
                a2 = fmaf(xv.z, wx4[r4].z, a2);
                a3 = fmaf(xv.w, wx4[r4].w, a3);
            }
        }
        const float4* hb4 = (const float4*)hbufs;
        #pragma unroll
        for (int k4 = 0; k4 < 8; ++k4){
            float4 hv = hb4[(half << 3) + k4];
            a0 = fmaf(hv.x, wh4[k4].x, a0);
            a1 = fmaf(hv.y, wh4[k4].y, a1);
            a2 = fmaf(hv.z, wh4[k4].z, a2);
            a3 = fmaf(hv.w, wh4[k4].w, a3);
        }
        zp[(half << 8) + col] = (a0 + a1) + (a2 + a3);
        __syncthreads();
        if (j < 64){
            float zi = zp[j]       + zp[256 + j];
            float zf = zp[64 + j]  + zp[320 + j];
            float zg = zp[128 + j] + zp[384 + j];
            float zo = zp[192 + j] + zp[448 + j];
            c = sigf(zf) * c + sigf(zi) * tanh_(zg);
            float h = sigf(zo) * tanh_(c);
            hbufs[j] = h;
            ccb[(size_t)t * 128 + j] = h;
        }
        __syncthreads();
    }
    if (j < 64){ st1[sidx] = c; st1[4096 + sidx] = hbufs[j]; }
}

// ---------- GEMM: C[M][ldc] = op(A @ B + bias). BM=128, BN=64, BK=64.
// 128 threads, 8x8 micro. LDS pads (129/68) keep bank aliasing <=2-way (free).
template<bool TANH>
__global__ __launch_bounds__(128) void k_gemm(
        const float* __restrict__ A, int lda,
        const float* __restrict__ B, int ldb,
        const float* __restrict__ bias,
        float* __restrict__ Cm, int ldc, int K){
    __shared__ float As[64 * 129];   // transposed: As[k][r]
    __shared__ float Bs[64 * 68];    // Bs[k][n]
    int tid = threadIdx.x;
    int tx = tid & 7;
    int ty = tid >> 3;
    int r0 = blockIdx.x * 128;
    int n0 = blockIdx.y * 64;
    float acc[8][8];
    #pragma unroll
    for (int i = 0; i < 8; ++i)
        #pragma unroll
        for (int n = 0; n < 8; ++n) acc[i][n] = 0.f;

    for (int kb = 0; kb < K; kb += 64){
        __syncthreads();
        for (int idx = tid; idx < 2048; idx += 128){
            int r = idx >> 4, k4 = idx & 15;
            float4 v = *(const float4*)(A + (size_t)(r0 + r) * lda + kb + k4*4);
            As[(k4*4 + 0)*129 + r] = v.x;
            As[(k4*4 + 1)*129 + r] = v.y;
            As[(k4*4 + 2)*129 + r] = v.z;
            As[(k4*4 + 3)*129 + r] = v.w;
        }
        for (int idx = tid; idx < 1024; idx += 128){
            int n4 = idx & 15, k = idx >> 4;
            float4 v = *(const float4*)(B + (size_t)(kb + k) * ldb + n0 + n4*4);
            *(float4*)(Bs + k*68 + n4*4) = v;
        }
        __syncthreads();
        #pragma unroll 4
        for (int k = 0; k < 64; ++k){
            float a[8];
            #pragma unroll
            for (int i = 0; i < 8; ++i) a[i] = As[k*129 + ty*8 + i];
            float4 b0 = *(const float4*)(Bs + k*68 + tx*8);
            float4 b1 = *(const float4*)(Bs + k*68 + tx*8 + 4);
            float bq[8] = {b0.x, b0.y, b0.z, b0.w, b1.x, b1.y, b1.z, b1.w};
            #pragma unroll
            for (int i = 0; i < 8; ++i)
                #pragma unroll
                for (int n = 0; n < 8; ++n) acc[i][n] += a[i] * bq[n];
        }
    }
    #pragma unroll
    for (int i = 0; i < 8; ++i){
        size_t rr = (size_t)r0 + ty*8 + i;
        float* cp = Cm + rr * ldc + n0 + tx*8;
        float ov[8];
        #pragma unroll
        for (int n = 0; n < 8; ++n){
            float v = acc[i][n] + bias[n0 + tx*8 + n];
            ov[n] = TANH ? tanh_(v) : v;
        }
        *(float4*)cp       = make_float4(ov[0], ov[1], ov[2], ov[3]);
        *(float4*)(cp + 4) = make_float4(ov[4], ov[5], ov[6], ov[7]);
    }
}

// ---------- layer-2 scan chunk (LSTM3 l=0 / LSTM4 l=1), state in st2.
// One WG per (lstm, batch); 1024 threads = (col 0..511, half 0..1).
// Each thread holds 64 contiguous WhT weights (16 float4) in VGPRs.
__global__ void __launch_bounds__(1024)
__attribute__((amdgpu_waves_per_eu(4, 4)))
k_scan2(const float* __restrict__ xg, const float* __restrict__ WhT2,
        float* __restrict__ enc, float* __restrict__ st2, int C){
    int l = blockIdx.x >> 5;
    int b = blockIdx.x & 31;
    int j = threadIdx.x;
    int col = j & 511;
    int half = j >> 9;
    float4 wh4[16];
    {
        const float4* wp = (const float4*)(WhT2 + ((size_t)l*512 + col)*128 + half*64);
        #pragma unroll
        for (int i = 0; i < 16; ++i) wh4[i] = wp[i];
    }

    __shared__ float zp[1024];      // [half][col]
    __shared__ float hbufs[128];
    float c = 0.f;
    int sidx = (l*32 + b)*128 + (j & 127);
    if (j < 128){ c = st2[sidx]; hbufs[j] = st2[8192 + sidx]; }
    __syncthreads();

    const float* xp = xg + ((size_t)b * C) * 1024 + (l << 9) + col;
    float* encb = enc + ((size_t)b * C) * 256 + (l << 7);

    float xnext = (half == 0) ? xp[0] : 0.f;
    for (int t = 0; t < C; ++t){
        float a0 = 0.f, a1 = 0.f, a2 = 0.f, a3 = 0.f;
        const float4* hb4 = (const float4*)hbufs;
        #pragma unroll
        for (int k4 = 0; k4 < 16; ++k4){
            float4 hv = hb4[(half << 4) + k4];
            a0 = fmaf(hv.x, wh4[k4].x, a0);
            a1 = fmaf(hv.y, wh4[k4].y, a1);
            a2 = fmaf(hv.z, wh4[k4].z, a2);
            a3 = fmaf(hv.w, wh4[k4].w, a3);
        }
        float z = (a0 + a1) + (a2 + a3);
        if (half == 0){
            z += xnext;
            int tn = (t + 1 < C) ? t + 1 : t;
            xnext = xp[(size_t)tn * 1024];      // prefetch next step's xg
        }
        zp[(half << 9) + col] = z;
        __syncthreads();
        if (j < 128){
            float zi = zp[j]        + zp[512 + j];
            float zf = zp[128 + j]  + zp[640 + j];
            float zg = zp[256 + j]  + zp[768 + j];
            float zo = zp[384 + j]  + zp[896 + j];
            c = sigf(zf) * c + sigf(zi) * tanh_(zg);
            float h = sigf(zo) * tanh_(c);
            hbufs[j] = h;
            encb[(size_t)t * 256 + j] = h;
        }
        __syncthreads();
    }
    if (j < 128){ st2[sidx] = c; st2[8192 + sidx] = hbufs[j]; }
}

// ---------- score = u @ Va + bva  (u = tanh(enc@Wa+ba) from GEMM<true>)
__global__ __launch_bounds__(256) void k_scorev(const float* __restrict__ u,
        const float* __restrict__ Va, const float* __restrict__ bva,
        float* __restrict__ sc){
    int m = blockIdx.x * 256 + threadIdx.x;
    const float4* up = (const float4*)(u + (size_t)m * 64);
    const float4* vp = (const float4*)Va;
    float acc = 0.f;
    #pragma unroll
    for (int i = 0; i < 16; ++i){
        float4 v = up[i], w = vp[i];
        acc += v.x*w.x + v.y*w.y + v.z*w.z + v.w*w.w;
    }
    sc[m] = acc + bva[0];
}

// ---------- online-softmax attention accumulate over one chunk.
// Per batch b: m,l,acc[256] updated flash-style. 1 WG/b, 1024 threads,
// t-range split 4-way (thread = (feature 0..255, slice 0..3)).
__global__ __launch_bounds__(1024) void k_attn(const float* __restrict__ sc,
        const float* __restrict__ enc, float* __restrict__ am,
        float* __restrict__ al, float* __restrict__ acc, int C){
    int b = blockIdx.x, tid = threadIdx.x;
    __shared__ float es[1024];
    __shared__ float red[16];
    __shared__ float sh[2];
    const float* sp = sc + (size_t)b * C;
    float mloc = -3.4e38f;
    for (int t = tid; t < C; t += 1024) mloc = fmaxf(mloc, sp[t]);
    #pragma unroll
    for (int off = 32; off; off >>= 1) mloc = fmaxf(mloc, __shfl_down(mloc, off));
    if ((tid & 63) == 0) red[tid >> 6] = mloc;
    __syncthreads();
    if (tid == 0){
        float mc = -3.4e38f;
        #pragma unroll
        for (int i = 0; i < 16; ++i) mc = fmaxf(mc, red[i]);
        float mo = am[b];
        float mn = fmaxf(mo, mc);
        sh[0] = mn;
        sh[1] = fexp2(1.44269504f * (mo - mn));   // alpha (0 on first chunk)
        am[b] = mn;
    }
    __syncthreads();
    float mn = sh[0], alpha = sh[1];
    float eloc = 0.f;
    for (int t = tid; t < C; t += 1024){
        float e = fexp2(1.44269504f * (sp[t] - mn));
        es[t] = e; eloc += e;
    }
    #pragma unroll
    for (int off = 32; off; off >>= 1) eloc += __shfl_down(eloc, off);
    if ((tid & 63) == 0) red[tid >> 6] = eloc;
    __syncthreads();
    if (tid == 0){
        float s = 0.f;
        #pragma unroll
        for (int i = 0; i < 16; ++i) s += red[i];
        al[b] = al[b] * alpha + s;
    }
    // partial acc over slice sl of the t-range (es[] ready: barrier above)
    int jf = tid & 255, sl = tid >> 8;
    int tlen = C >> 2;
    const float* ep = enc + ((size_t)b * C + (size_t)sl * tlen) * 256 + jf;
    const float* eb = es + sl * tlen;
    float a = 0.f;
    for (int t = 0; t < tlen; ++t) a = fmaf(eb[t], ep[(size_t)t * 256], a);
    __syncthreads();
    es[tid] = a;
    __syncthreads();
    if (tid < 256)
        acc[b*256 + tid] = acc[b*256 + tid] * alpha
                         + ((es[tid] + es[256 + tid]) + (es[512 + tid] + es[768 + tid]));
}

// ---------- head: ctx = acc/l, h1 = tanh(ctx@Wd1+bd1), out = h1@Wd2+bd2
__global__ __launch_bounds__(256) void k_head(const float* __restrict__ acc,
        const float* __restrict__ al,
        const float* __restrict__ Wd1, const float* __restrict__ bd1,
        const float* __restrict__ Wd2, const float* __restrict__ bd2,
        float* __restrict__ out){
    __shared__ float ctxs[32 * 256];
    __shared__ float h1s[32 * 64];
    int tid = threadIdx.x;
    for (int idx = tid; idx < 8192; idx += 256){
        int b = idx >> 8;
        ctxs[idx] = acc[idx] / al[b];
    }
    __syncthreads();
    for (int idx = tid; idx < 2048; idx += 256){
        int b = idx >> 6, n = idx & 63;
        float a = bd1[n];
        for (int i = 0; i < 256; ++i) a += ctxs[b*256 + i] * Wd1[i*64 + n];
        h1s[idx] = tanh_(a);
    }
    __syncthreads();
    if (tid < 32){
        float a = bd2[0];
        #pragma unroll
        for (int n = 0; n < 64; ++n) a += h1s[tid*64 + n] * Wd2[n];
        out[tid] = a;
    }
}

// ============================================================================
extern "C" void kernel_launch(void* const* d_in, const int* in_sizes, int n_in,
                              void* d_out, int out_size, void* d_ws, size_t ws_size,
                              hipStream_t stream){
    const float* X     = (const float*)d_in[0];
    const float* convw = (const float*)d_in[1];
    const float* convb = (const float*)d_in[2];
    const float* Wx1 = (const float*)d_in[3];
    const float* Wh1 = (const float*)d_in[4];
    const float* b1  = (const float*)d_in[5];
    const float* Wx2 = (const float*)d_in[6];
    const float* Wh2 = (const float*)d_in[7];
    const float* b2  = (const float*)d_in[8];
    const float* Wx3 = (const float*)d_in[9];
    const float* Wh3 = (const float*)d_in[10];
    const float* b3  = (const float*)d_in[11];
    const float* Wx4 = (const float*)d_in[12];
    const float* Wh4 = (const float*)d_in[13];
    const float* b4  = (const float*)d_in[14];
    const float* Wa  = (const float*)d_in[15];
    const float* ba  = (const float*)d_in[16];
    const float* Va  = (const float*)d_in[17];
    const float* bva = (const float*)d_in[18];
    const float* Wd1 = (const float*)d_in[19];
    const float* bd1 = (const float*)d_in[20];
    const float* Wd2 = (const float*)d_in[21];
    const float* bd2 = (const float*)d_in[22];
    float* out = (float*)d_out;
    (void)in_sizes; (void)n_in; (void)out_size;

    // ---- choose chunk size C so everything fits in ws_size ----
    const size_t fixedFl = 131072 + 1024 + 131072 + 32768 + 8192 + 512
                         + 8192 + 16384 + 32 + 32 + 8192 + 32*1024;
    size_t capFl = ws_size / 4;
    int C = 1024;
    while (C > 32){
        size_t need = fixedFl + (size_t)NB * C * (16 + 128 + 1024 + 256 + 64);
        if (need <= capFl) break;
        C >>= 1;
    }
    int lc = 31 - __builtin_clz((unsigned)C);
    int nch = TFULL / C;

    float* ws   = (float*)d_ws;
    float* W34  = ws;                      // 131072
    float* b34  = W34 + 131072;            // 1024
    float* WhT2 = b34 + 1024;              // 131072
    float* WhT1 = WhT2 + 131072;           // 32768
    float* WxT1 = WhT1 + 32768;            // 8192
    float* b12  = WxT1 + 8192;             // 512
    float* st1  = b12 + 512;               // 8192  (c | h)
    float* st2  = st1 + 8192;              // 16384 (c | h)
    float* am   = st2 + 16384;             // 32
    float* al   = am + 32;                 // 32
    float* acc  = al + 32;                 // 8192
    float* scb  = acc + 8192;              // 32*1024
    float* xcv  = scb + 32*1024;           // 32*C*16
    float* ccb  = xcv + (size_t)NB*C*16;   // 32*C*128
    float* xgb  = ccb + (size_t)NB*C*128;  // 32*C*1024
    float* enb  = xgb + (size_t)NB*C*1024; // 32*C*256
    float* ub   = enb + (size_t)NB*C*256;  // 32*C*64

    k_init<<<64, 256, 0, stream>>>(st1, st2, am, al, acc);
    k_pack<<<512, 256, 0, stream>>>(Wx1, Wh1, b1, Wx2, Wh2, b2,
                                    Wx3, Wh3, b3, Wx4, Wh4, b4,
                                    W34, b34, WhT2, WhT1, WxT1, b12);

    for (int ch = 0; ch < nch; ++ch){
        int t0 = ch * C;
        k_conv<<<NB*C/256, 256, 0, stream>>>(X, convw, convb, xcv, t0, lc);
        k_scan1<<<64, 512, 0, stream>>>(xcv, WxT1, WhT1, b12, ccb, st1, C);
        // xg = cc @ W34 + b34 : M=32*C, K=128, N=1024
        k_gemm<false><<<dim3(NB*C/128, 16), 128, 0, stream>>>(
            ccb, 128, W34, 1024, b34, xgb, 1024, 128);
        k_scan2<<<64, 1024, 0, stream>>>(xgb, WhT2, enb, st2, C);
        // u = tanh(enc @ Wa + ba) : M=32*C, K=256, N=64
        k_gemm<true><<<dim3(NB*C/128, 1), 128, 0, stream>>>(
            enb, 256, Wa, 64, ba, ub, 64, 256);
        k_scorev<<<NB*C/256, 256, 0, stream>>>(ub, Va, bva, scb);
        k_attn<<<32, 1024, 0, stream>>>(scb, enb, am, al, acc, C);
    }
    k_head<<<1, 256, 0, stream>>>(acc, al, Wd1, bd1, Wd2, bd2, out);
}

// Round 5
// 5979.359 us; speedup vs baseline: 1.0684x; 1.0684x over previous
//
#include <hip/hip_runtime.h>

// ============================================================================
// LSTM+attention+MLP forward, fp32 throughout. T-chunked pipeline with
// online-softmax attention so the workspace fits any reasonable ws_size.
// B=32, T=4096, conv 8->16 (k=4 SAME), LSTM1/2: 16->64, LSTM3/4: 128->128.
// Feature-axis flips fold into row-flips of Wx2 / Wx4.
// Scans: thread = (col-quad, k-slice); per-thread weights packed contiguous
// and pinned in VGPRs via asm launder (volatile asm can't be rematerialized).
// ============================================================================

#define TFULL 4096
#define NB 32

// ---------- fast math helpers (f32, ~1e-7 rel) ----------
__device__ __forceinline__ float fexp2(float x){ return __builtin_amdgcn_exp2f(x); }
__device__ __forceinline__ float frcp(float x){ return __builtin_amdgcn_rcpf(x); }
__device__ __forceinline__ float sigf(float x){ return frcp(1.f + fexp2(-1.44269504f*x)); }
__device__ __forceinline__ float tanh_(float x){
    float e = fexp2(fminf(2.88539008f*x, 126.f));   // exp(2x), clamp avoids inf-inf
    return (e - 1.f) * frcp(e + 1.f);
}
#define PIN4(v) asm volatile("" : "+v"(v.x), "+v"(v.y), "+v"(v.z), "+v"(v.w))

// ---------- init persistent state ----------
__global__ __launch_bounds__(256) void k_init(float* __restrict__ st1,
        float* __restrict__ st2, float* __restrict__ am, float* __restrict__ al,
        float* __restrict__ acc){
    int i = blockIdx.x * 256 + threadIdx.x;       // grid 64 -> i < 16384
    if (i < 8192)  st1[i] = 0.f;
    if (i < 16384) st2[i] = 0.f;
    if (i < 8192)  acc[i] = 0.f;
    if (i < 32){ am[i] = -3.4e38f; al[i] = 0.f; }
}

// ---------- one-time weight packing ----------
// W34 [128][1024] = [Wx3 | flipRows(Wx4)], b34 [1024]
// W2p [l][tid 1024][64]: per-thread scan2 weights; tid=(s<<7)|q, w=c*16+k ->
//      Wh34[(s*16+k)*512 + (4q+c)]
// W1p [l][tid 512][64]:  per-thread scan1 weights; tid=(s<<6)|q;
//      w<32: c=w>>3,k=w&7 -> Wh12[(s*8+k)*256 + 4q+c]
//      w>=32 (s<2 only): c,r -> Wx12[(s*8+r) row, flipped for l=1]
// b12 [l][256]
__global__ __launch_bounds__(256) void k_pack(
        const float* __restrict__ Wx1, const float* __restrict__ Wh1, const float* __restrict__ b1,
        const float* __restrict__ Wx2, const float* __restrict__ Wh2, const float* __restrict__ b2,
        const float* __restrict__ Wx3, const float* __restrict__ Wh3, const float* __restrict__ b3,
        const float* __restrict__ Wx4, const float* __restrict__ Wh4, const float* __restrict__ b4,
        float* __restrict__ W34, float* __restrict__ b34, float* __restrict__ W2p,
        float* __restrict__ W1p, float* __restrict__ b12){
    int i0 = blockIdx.x * 256 + threadIdx.x;
    int stride = gridDim.x * 256;
    for (int e = i0; e < 131072; e += stride){
        int k = e >> 10, n = e & 1023;
        W34[e] = (n < 512) ? Wx3[k*512 + n] : Wx4[(127 - k)*512 + (n - 512)];
    }
    for (int e = i0; e < 1024; e += stride) b34[e] = (e < 512) ? b3[e] : b4[e - 512];
    for (int e = i0; e < 131072; e += stride){
        int l = e >> 16, r = e & 65535, tid = r >> 6, wq = r & 63;
        int q = tid & 127, s = tid >> 7;
        int c = wq >> 4, k = wq & 15;
        W2p[e] = (l ? Wh4 : Wh3)[(s*16 + k)*512 + (4*q + c)];
    }
    for (int e = i0; e < 65536; e += stride){
        int l = e >> 15, r = e & 32767, tid = r >> 6, wq = r & 63;
        int q = tid & 63, s = tid >> 6;
        float v = 0.f;
        if (wq < 32){
            int c = wq >> 3, k = wq & 7;
            v = (l ? Wh2 : Wh1)[(s*8 + k)*256 + (4*q + c)];
        } else if (s < 2){
            int c = (wq - 32) >> 3, rr = (wq - 32) & 7;
            int rg = s*8 + rr, col = 4*q + c;
            v = l ? Wx2[(15 - rg)*256 + col] : Wx1[rg*256 + col];
        }
        W1p[e] = v;
    }
    for (int e = i0; e < 512; e += stride) b12[e] = (e < 256) ? b1[e] : b2[e - 256];
}

// ---------- conv1d chunk: rows [t0, t0+C) -> xcv[(b*C+trel)][16]
__global__ __launch_bounds__(256) void k_conv(const float* __restrict__ X,
        const float* __restrict__ W, const float* __restrict__ Bv,
        float* __restrict__ out, int t0, int lc){
    __shared__ float Ws[512];
    __shared__ float bs[16];
    int tid = threadIdx.x;
    Ws[tid] = W[tid]; Ws[tid + 256] = W[tid + 256];
    if (tid < 16) bs[tid] = Bv[tid];
    __syncthreads();
    int m = blockIdx.x * 256 + tid;               // b*C + trel
    int b = m >> lc, trel = m & ((1 << lc) - 1);
    int t = t0 + trel;
    float o[16];
    #pragma unroll
    for (int co = 0; co < 16; ++co) o[co] = bs[co];
    #pragma unroll
    for (int w = 0; w < 4; ++w){
        int tt = t + w - 1;
        if (tt >= 0 && tt < TFULL){
            const float* xr = X + ((size_t)(b << 12) + tt) * 8;
            #pragma unroll
            for (int ci = 0; ci < 8; ++ci){
                float v = xr[ci];
                #pragma unroll
                for (int co = 0; co < 16; ++co) o[co] += v * Ws[(w*8 + ci)*16 + co];
            }
        }
    }
    float* op = out + (size_t)m * 16;
    #pragma unroll
    for (int q = 0; q < 4; ++q)
        *(float4*)(op + q*4) = make_float4(o[q*4], o[q*4+1], o[q*4+2], o[q*4+3]);
}

// ---------- layer-1 scan chunk: LSTM1 (l=0) / LSTM2 (l=1, row-flipped Wx).
// One WG per (lstm, batch); 512 threads = (col-quad q 0..63, slice s 0..7).
// slice s: h[8s..8s+8); s<2 additionally x rows [8s..8s+8).
__global__ void
__attribute__((amdgpu_flat_work_group_size(512, 512), amdgpu_waves_per_eu(2, 2)))
k_scan1(const float* __restrict__ x, const float* __restrict__ W1p,
        const float* __restrict__ b12,
        float* __restrict__ cc, float* __restrict__ st1, int C){
    int l = blockIdx.x >> 5;
    int b = blockIdx.x & 31;
    int tid = threadIdx.x;
    int q = tid & 63;
    int s = tid >> 6;
    float4 w[16];
    {
        const float4* wp = (const float4*)(W1p + ((size_t)l*512 + tid)*64);
        #pragma unroll
        for (int i = 0; i < 16; ++i) w[i] = wp[i];
        #pragma unroll
        for (int i = 0; i < 16; ++i) PIN4(w[i]);
    }
    float bi0 = 0.f, bi1 = 0.f, bi2 = 0.f, bi3 = 0.f;
    if (tid < 64){
        bi0 = b12[l*256 + tid];       bi1 = b12[l*256 + 64 + tid];
        bi2 = b12[l*256 + 128 + tid]; bi3 = b12[l*256 + 192 + tid];
    }

    __shared__ float xs[128 * 16];   // up-to-128-step input tile
    __shared__ float zp[8 * 256];    // [s][col]
    __shared__ float hbufs[64];
    float c = 0.f;
    int sidx = (l*32 + b)*64 + (tid & 63);
    if (tid < 64){ c = st1[sidx]; hbufs[tid] = st1[4096 + sidx]; }
    __syncthreads();

    const float* xb = x + ((size_t)b * C) * 16;
    float* ccb = cc + ((size_t)b * C) * 128 + (l << 6);

    for (int t = 0; t < C; ++t){
        int st = t & 127;
        if (st == 0){
            __syncthreads();
            const float4* src = (const float4*)(xb + (size_t)t * 16);
            float4* dst = (float4*)xs;
            if (t + (tid >> 2) < C) dst[tid] = src[tid];
            __syncthreads();
        }
        float a0 = 0.f, a1 = 0.f, a2 = 0.f, a3 = 0.f;
        const float4* hb4 = (const float4*)hbufs + (s << 1);
        #pragma unroll
        for (int k4 = 0; k4 < 2; ++k4){
            float4 hv = hb4[k4];
            a0 = fmaf(hv.x, w[k4].x, a0);     a0 = fmaf(hv.y, w[k4].y, a0);
            a0 = fmaf(hv.z, w[k4].z, a0);     a0 = fmaf(hv.w, w[k4].w, a0);
            a1 = fmaf(hv.x, w[2+k4].x, a1);   a1 = fmaf(hv.y, w[2+k4].y, a1);
            a1 = fmaf(hv.z, w[2+k4].z, a1);   a1 = fmaf(hv.w, w[2+k4].w, a1);
            a2 = fmaf(hv.x, w[4+k4].x, a2);   a2 = fmaf(hv.y, w[4+k4].y, a2);
            a2 = fmaf(hv.z, w[4+k4].z, a2);   a2 = fmaf(hv.w, w[4+k4].w, a2);
            a3 = fmaf(hv.x, w[6+k4].x, a3);   a3 = fmaf(hv.y, w[6+k4].y, a3);
            a3 = fmaf(hv.z, w[6+k4].z, a3);   a3 = fmaf(hv.w, w[6+k4].w, a3);
        }
        if (s < 2){   // wave-uniform: x contribution
            const float4* xr = (const float4*)(xs + st * 16) + (s << 1);
            #pragma unroll
            for (int r4 = 0; r4 < 2; ++r4){
                float4 xv = xr[r4];
                a0 = fmaf(xv.x, w[8+r4].x, a0);    a0 = fmaf(xv.y, w[8+r4].y, a0);
                a0 = fmaf(xv.z, w[8+r4].z, a0);    a0 = fmaf(xv.w, w[8+r4].w, a0);
                a1 = fmaf(xv.x, w[10+r4].x, a1);   a1 = fmaf(xv.y, w[10+r4].y, a1);
                a1 = fmaf(xv.z, w[10+r4].z, a1);   a1 = fmaf(xv.w, w[10+r4].w, a1);
                a2 = fmaf(xv.x, w[12+r4].x, a2);   a2 = fmaf(xv.y, w[12+r4].y, a2);
                a2 = fmaf(xv.z, w[12+r4].z, a2);   a2 = fmaf(xv.w, w[12+r4].w, a2);
                a3 = fmaf(xv.x, w[14+r4].x, a3);   a3 = fmaf(xv.y, w[14+r4].y, a3);
                a3 = fmaf(xv.z, w[14+r4].z, a3);   a3 = fmaf(xv.w, w[14+r4].w, a3);
            }
        }
        *(float4*)(zp + (s << 8) + (q << 2)) = make_float4(a0, a1, a2, a3);
        __syncthreads();
        if (tid < 64){
            float zi = bi0, zf = bi1, zg = bi2, zo = bi3;
            #pragma unroll
            for (int ss = 0; ss < 8; ++ss){
                const float* zr = zp + (ss << 8);
                zi += zr[tid]; zf += zr[64 + tid]; zg += zr[128 + tid]; zo += zr[192 + tid];
            }
            c = sigf(zf) * c + sigf(zi) * tanh_(zg);
            float h = sigf(zo) * tanh_(c);
            hbufs[tid] = h;
            ccb[(size_t)t * 128 + tid] = h;
        }
        __syncthreads();
    }
    if (tid < 64){ st1[sidx] = c; st1[4096 + sidx] = hbufs[tid]; }
}

// ---------- GEMM: C[M][ldc] = op(A @ B + bias). BM=128, BN=64, BK=64.
// 128 threads, 8x8 micro. LDS pads (129/68) keep bank aliasing <=2-way (free).
template<bool TANH>
__global__ __launch_bounds__(128) void k_gemm(
        const float* __restrict__ A, int lda,
        const float* __restrict__ B, int ldb,
        const float* __restrict__ bias,
        float* __restrict__ Cm, int ldc, int K){
    __shared__ float As[64 * 129];   // transposed: As[k][r]
    __shared__ float Bs[64 * 68];    // Bs[k][n]
    int tid = threadIdx.x;
    int tx = tid & 7;
    int ty = tid >> 3;
    int r0 = blockIdx.x * 128;
    int n0 = blockIdx.y * 64;
    float acc[8][8];
    #pragma unroll
    for (int i = 0; i < 8; ++i)
        #pragma unroll
        for (int n = 0; n < 8; ++n) acc[i][n] = 0.f;

    for (int kb = 0; kb < K; kb += 64){
        __syncthreads();
        for (int idx = tid; idx < 2048; idx += 128){
            int r = idx >> 4, k4 = idx & 15;
            float4 v = *(const float4*)(A + (size_t)(r0 + r) * lda + kb + k4*4);
            As[(k4*4 + 0)*129 + r] = v.x;
            As[(k4*4 + 1)*129 + r] = v.y;
            As[(k4*4 + 2)*129 + r] = v.z;
            As[(k4*4 + 3)*129 + r] = v.w;
        }
        for (int idx = tid; idx < 1024; idx += 128){
            int n4 = idx & 15, k = idx >> 4;
            float4 v = *(const float4*)(B + (size_t)(kb + k) * ldb + n0 + n4*4);
            *(float4*)(Bs + k*68 + n4*4) = v;
        }
        __syncthreads();
        #pragma unroll 4
        for (int k = 0; k < 64; ++k){
            float a[8];
            #pragma unroll
            for (int i = 0; i < 8; ++i) a[i] = As[k*129 + ty*8 + i];
            float4 b0 = *(const float4*)(Bs + k*68 + tx*8);
            float4 b1 = *(const float4*)(Bs + k*68 + tx*8 + 4);
            float bq[8] = {b0.x, b0.y, b0.z, b0.w, b1.x, b1.y, b1.z, b1.w};
            #pragma unroll
            for (int i = 0; i < 8; ++i)
                #pragma unroll
                for (int n = 0; n < 8; ++n) acc[i][n] += a[i] * bq[n];
        }
    }
    #pragma unroll
    for (int i = 0; i < 8; ++i){
        size_t rr = (size_t)r0 + ty*8 + i;
        float* cp = Cm + rr * ldc + n0 + tx*8;
        float ov[8];
        #pragma unroll
        for (int n = 0; n < 8; ++n){
            float v = acc[i][n] + bias[n0 + tx*8 + n];
            ov[n] = TANH ? tanh_(v) : v;
        }
        *(float4*)cp       = make_float4(ov[0], ov[1], ov[2], ov[3]);
        *(float4*)(cp + 4) = make_float4(ov[4], ov[5], ov[6], ov[7]);
    }
}

// ---------- layer-2 scan chunk (LSTM3 l=0 / LSTM4 l=1), state in st2.
// One WG per (lstm, batch); 1024 threads = (col-quad q 0..127, slice s 0..7).
// Thread: 4 cols x 16 k; 64 weights pinned in VGPRs. s==0 waves add xg.
__global__ void
__attribute__((amdgpu_flat_work_group_size(1024, 1024), amdgpu_waves_per_eu(4, 4)))
k_scan2(const float* __restrict__ xg, const float* __restrict__ W2p,
        float* __restrict__ enc, float* __restrict__ st2, int C){
    int l = blockIdx.x >> 5;
    int b = blockIdx.x & 31;
    int tid = threadIdx.x;
    int q = tid & 127;
    int s = tid >> 7;
    float4 w[16];
    {
        const float4* wp = (const float4*)(W2p + ((size_t)l*1024 + tid)*64);
        #pragma unroll
        for (int i = 0; i < 16; ++i) w[i] = wp[i];
        #pragma unroll
        for (int i = 0; i < 16; ++i) PIN4(w[i]);
    }

    __shared__ float zp[8 * 512];    // [s][col]
    __shared__ float hbufs[128];
    float c = 0.f;
    int sidx = (l*32 + b)*128 + (tid & 127);
    if (tid < 128){ c = st2[sidx]; hbufs[tid] = st2[8192 + sidx]; }
    __syncthreads();

    const float4* xp4 = (const float4*)(xg + ((size_t)b * C) * 1024 + (l << 9)) + q;
    float* encb = enc + ((size_t)b * C) * 256 + (l << 7);

    float4 xn = make_float4(0.f, 0.f, 0.f, 0.f);
    if (s == 0) xn = xp4[0];
    for (int t = 0; t < C; ++t){
        float a0, a1, a2, a3;
        if (s == 0){   // wave-uniform: xg (incl. bias) + prefetch next step
            a0 = xn.x; a1 = xn.y; a2 = xn.z; a3 = xn.w;
            int tn = (t + 1 < C) ? t + 1 : t;
            xn = xp4[(size_t)tn * 256];
        } else { a0 = a1 = a2 = a3 = 0.f; }
        const float4* hb4 = (const float4*)hbufs + (s << 2);
        #pragma unroll
        for (int k4 = 0; k4 < 4; ++k4){
            float4 hv = hb4[k4];
            a0 = fmaf(hv.x, w[k4].x, a0);      a0 = fmaf(hv.y, w[k4].y, a0);
            a0 = fmaf(hv.z, w[k4].z, a0);      a0 = fmaf(hv.w, w[k4].w, a0);
            a1 = fmaf(hv.x, w[4+k4].x, a1);    a1 = fmaf(hv.y, w[4+k4].y, a1);
            a1 = fmaf(hv.z, w[4+k4].z, a1);    a1 = fmaf(hv.w, w[4+k4].w, a1);
            a2 = fmaf(hv.x, w[8+k4].x, a2);    a2 = fmaf(hv.y, w[8+k4].y, a2);
            a2 = fmaf(hv.z, w[8+k4].z, a2);    a2 = fmaf(hv.w, w[8+k4].w, a2);
            a3 = fmaf(hv.x, w[12+k4].x, a3);   a3 = fmaf(hv.y, w[12+k4].y, a3);
            a3 = fmaf(hv.z, w[12+k4].z, a3);   a3 = fmaf(hv.w, w[12+k4].w, a3);
        }
        *(float4*)(zp + (s << 9) + (q << 2)) = make_float4(a0, a1, a2, a3);
        __syncthreads();
        if (tid < 128){
            float zi = 0.f, zf = 0.f, zg = 0.f, zo = 0.f;
            #pragma unroll
            for (int ss = 0; ss < 8; ++ss){
                const float* zr = zp + (ss << 9);
                zi += zr[tid]; zf += zr[128 + tid]; zg += zr[256 + tid]; zo += zr[384 + tid];
            }
            c = sigf(zf) * c + sigf(zi) * tanh_(zg);
            float h = sigf(zo) * tanh_(c);
            hbufs[tid] = h;
            encb[(size_t)t * 256 + tid] = h;
        }
        __syncthreads();
    }
    if (tid < 128){ st2[sidx] = c; st2[8192 + sidx] = hbufs[tid]; }
}

// ---------- score = u @ Va + bva  (u = tanh(enc@Wa+ba) from GEMM<true>)
__global__ __launch_bounds__(256) void k_scorev(const float* __restrict__ u,
        const float* __restrict__ Va, const float* __restrict__ bva,
        float* __restrict__ sc){
    int m = blockIdx.x * 256 + threadIdx.x;
    const float4* up = (const float4*)(u + (size_t)m * 64);
    const float4* vp = (const float4*)Va;
    float acc = 0.f;
    #pragma unroll
    for (int i = 0; i < 16; ++i){
        float4 v = up[i], w = vp[i];
        acc += v.x*w.x + v.y*w.y + v.z*w.z + v.w*w.w;
    }
    sc[m] = acc + bva[0];
}

// ---------- online-softmax attention accumulate over one chunk.
// Per batch b: m,l,acc[256] updated flash-style. 1 WG/b, 1024 threads,
// t-range split 4-way (thread = (feature 0..255, slice 0..3)).
__global__ __launch_bounds__(1024) void k_attn(const float* __restrict__ sc,
        const float* __restrict__ enc, float* __restrict__ am,
        float* __restrict__ al, float* __restrict__ acc, int C){
    int b = blockIdx.x, tid = threadIdx.x;
    __shared__ float es[1024];
    __shared__ float red[16];
    __shared__ float sh[2];
    const float* sp = sc + (size_t)b * C;
    float mloc = -3.4e38f;
    for (int t = tid; t < C; t += 1024) mloc = fmaxf(mloc, sp[t]);
    #pragma unroll
    for (int off = 32; off; off >>= 1) mloc = fmaxf(mloc, __shfl_down(mloc, off));
    if ((tid & 63) == 0) red[tid >> 6] = mloc;
    __syncthreads();
    if (tid == 0){
        float mc = -3.4e38f;
        #pragma unroll
        for (int i = 0; i < 16; ++i) mc = fmaxf(mc, red[i]);
        float mo = am[b];
        float mn = fmaxf(mo, mc);
        sh[0] = mn;
        sh[1] = fexp2(1.44269504f * (mo - mn));   // alpha (0 on first chunk)
        am[b] = mn;
    }
    __syncthreads();
    float mn = sh[0], alpha = sh[1];
    float eloc = 0.f;
    for (int t = tid; t < C; t += 1024){
        float e = fexp2(1.44269504f * (sp[t] - mn));
        es[t] = e; eloc += e;
    }
    #pragma unroll
    for (int off = 32; off; off >>= 1) eloc += __shfl_down(eloc, off);
    if ((tid & 63) == 0) red[tid >> 6] = eloc;
    __syncthreads();
    if (tid == 0){
        float sm = 0.f;
        #pragma unroll
        for (int i = 0; i < 16; ++i) sm += red[i];
        al[b] = al[b] * alpha + sm;
    }
    // partial acc over slice sl of the t-range (es[] ready: barrier above)
    int jf = tid & 255, sl = tid >> 8;
    int tlen = C >> 2;
    const float* ep = enc + ((size_t)b * C + (size_t)sl * tlen) * 256 + jf;
    const float* eb = es + sl * tlen;
    float a = 0.f;
    for (int t = 0; t < tlen; ++t) a = fmaf(eb[t], ep[(size_t)t * 256], a);
    __syncthreads();
    es[tid] = a;
    __syncthreads();
    if (tid < 256)
        acc[b*256 + tid] = acc[b*256 + tid] * alpha
                         + ((es[tid] + es[256 + tid]) + (es[512 + tid] + es[768 + tid]));
}

// ---------- head: ctx = acc/l, h1 = tanh(ctx@Wd1+bd1), out = h1@Wd2+bd2
__global__ __launch_bounds__(256) void k_head(const float* __restrict__ acc,
        const float* __restrict__ al,
        const float* __restrict__ Wd1, const float* __restrict__ bd1,
        const float* __restrict__ Wd2, const float* __restrict__ bd2,
        float* __restrict__ out){
    __shared__ float ctxs[32 * 256];
    __shared__ float h1s[32 * 64];
    int tid = threadIdx.x;
    for (int idx = tid; idx < 8192; idx += 256){
        int b = idx >> 8;
        ctxs[idx] = acc[idx] / al[b];
    }
    __syncthreads();
    for (int idx = tid; idx < 2048; idx += 256){
        int b = idx >> 6, n = idx & 63;
        float a = bd1[n];
        for (int i = 0; i < 256; ++i) a += ctxs[b*256 + i] * Wd1[i*64 + n];
        h1s[idx] = tanh_(a);
    }
    __syncthreads();
    if (tid < 32){
        float a = bd2[0];
        #pragma unroll
        for (int n = 0; n < 64; ++n) a += h1s[tid*64 + n] * Wd2[n];
        out[tid] = a;
    }
}

// ============================================================================
extern "C" void kernel_launch(void* const* d_in, const int* in_sizes, int n_in,
                              void* d_out, int out_size, void* d_ws, size_t ws_size,
                              hipStream_t stream){
    const float* X     = (const float*)d_in[0];
    const float* convw = (const float*)d_in[1];
    const float* convb = (const float*)d_in[2];
    const float* Wx1 = (const float*)d_in[3];
    const float* Wh1 = (const float*)d_in[4];
    const float* b1  = (const float*)d_in[5];
    const float* Wx2 = (const float*)d_in[6];
    const float* Wh2 = (const float*)d_in[7];
    const float* b2  = (const float*)d_in[8];
    const float* Wx3 = (const float*)d_in[9];
    const float* Wh3 = (const float*)d_in[10];
    const float* b3  = (const float*)d_in[11];
    const float* Wx4 = (const float*)d_in[12];
    const float* Wh4 = (const float*)d_in[13];
    const float* b4  = (const float*)d_in[14];
    const float* Wa  = (const float*)d_in[15];
    const float* ba  = (const float*)d_in[16];
    const float* Va  = (const float*)d_in[17];
    const float* bva = (const float*)d_in[18];
    const float* Wd1 = (const float*)d_in[19];
    const float* bd1 = (const float*)d_in[20];
    const float* Wd2 = (const float*)d_in[21];
    const float* bd2 = (const float*)d_in[22];
    float* out = (float*)d_out;
    (void)in_sizes; (void)n_in; (void)out_size;

    // ---- choose chunk size C so everything fits in ws_size ----
    const size_t fixedFl = 131072 + 1024 + 131072 + 65536 + 512
                         + 8192 + 16384 + 32 + 32 + 8192 + 32*1024;
    size_t capFl = ws_size / 4;
    int C = 1024;
    while (C > 32){
        size_t need = fixedFl + (size_t)NB * C * (16 + 128 + 1024 + 256 + 64);
        if (need <= capFl) break;
        C >>= 1;
    }
    int lc = 31 - __builtin_clz((unsigned)C);
    int nch = TFULL / C;

    float* ws   = (float*)d_ws;
    float* W34  = ws;                      // 131072
    float* b34  = W34 + 131072;            // 1024
    float* W2p  = b34 + 1024;              // 131072
    float* W1p  = W2p + 131072;            // 65536
    float* b12  = W1p + 65536;             // 512
    float* st1  = b12 + 512;               // 8192  (c | h)
    float* st2  = st1 + 8192;              // 16384 (c | h)
    float* am   = st2 + 16384;             // 32
    float* al   = am + 32;                 // 32
    float* acc  = al + 32;                 // 8192
    float* scb  = acc + 8192;              // 32*1024
    float* xcv  = scb + 32*1024;           // 32*C*16
    float* ccb  = xcv + (size_t)NB*C*16;   // 32*C*128
    float* xgb  = ccb + (size_t)NB*C*128;  // 32*C*1024
    float* enb  = xgb + (size_t)NB*C*1024; // 32*C*256
    float* ub   = enb + (size_t)NB*C*256;  // 32*C*64

    k_init<<<64, 256, 0, stream>>>(st1, st2, am, al, acc);
    k_pack<<<512, 256, 0, stream>>>(Wx1, Wh1, b1, Wx2, Wh2, b2,
                                    Wx3, Wh3, b3, Wx4, Wh4, b4,
                                    W34, b34, W2p, W1p, b12);

    for (int ch = 0; ch < nch; ++ch){
        int t0 = ch * C;
        k_conv<<<NB*C/256, 256, 0, stream>>>(X, convw, convb, xcv, t0, lc);
        k_scan1<<<64, 512, 0, stream>>>(xcv, W1p, b12, ccb, st1, C);
        // xg = cc @ W34 + b34 : M=32*C, K=128, N=1024
        k_gemm<false><<<dim3(NB*C/128, 16), 128, 0, stream>>>(
            ccb, 128, W34, 1024, b34, xgb, 1024, 128);
        k_scan2<<<64, 1024, 0, stream>>>(xgb, W2p, enb, st2, C);
        // u = tanh(enc @ Wa + ba) : M=32*C, K=256, N=64
        k_gemm<true><<<dim3(NB*C/128, 1), 128, 0, stream>>>(
            enb, 256, Wa, 64, ba, ub, 64, 256);
        k_scorev<<<NB*C/256, 256, 0, stream>>>(ub, Va, bva, scb);
        k_attn<<<32, 1024, 0, stream>>>(scb, enb, am, al, acc, C);
    }
    k_head<<<1, 256, 0, stream>>>(acc, al, Wd1, bd1, Wd2, bd2, out);
}

// Round 6
// 5658.493 us; speedup vs baseline: 1.1290x; 1.0567x over previous
//
#include <hip/hip_runtime.h>

// ============================================================================
// LSTM+attention+MLP forward, fp32 throughout. T-chunked pipeline with
// online-softmax attention so the workspace fits any reasonable ws_size.
// B=32, T=4096, conv 8->16 (k=4 SAME), LSTM1/2: 16->64, LSTM3/4: 128->128.
// Feature-axis flips fold into row-flips of Wx2 / Wx4.
// scan2: 512 thr x 128 weights/thread (col-quad x 4 k-slices). 512-thr WGs
// have a 256-VGPR/thread budget (2 waves/SIMD) so weights fit comfortably;
// PIN4 asm launder prevents spill-by-reload.
// ============================================================================

#define TFULL 4096
#define NB 32

// ---------- fast math helpers (f32, ~1e-7 rel) ----------
__device__ __forceinline__ float fexp2(float x){ return __builtin_amdgcn_exp2f(x); }
__device__ __forceinline__ float frcp(float x){ return __builtin_amdgcn_rcpf(x); }
__device__ __forceinline__ float sigf(float x){ return frcp(1.f + fexp2(-1.44269504f*x)); }
__device__ __forceinline__ float tanh_(float x){
    float e = fexp2(fminf(2.88539008f*x, 126.f));   // exp(2x), clamp avoids inf-inf
    return (e - 1.f) * frcp(e + 1.f);
}
#define PIN4(v) asm volatile("" : "+v"(v.x), "+v"(v.y), "+v"(v.z), "+v"(v.w))

// ---------- init persistent state ----------
__global__ __launch_bounds__(256) void k_init(float* __restrict__ st1,
        float* __restrict__ st2, float* __restrict__ am, float* __restrict__ al,
        float* __restrict__ acc){
    int i = blockIdx.x * 256 + threadIdx.x;       // grid 64 -> i < 16384
    if (i < 8192)  st1[i] = 0.f;
    if (i < 16384) st2[i] = 0.f;
    if (i < 8192)  acc[i] = 0.f;
    if (i < 32){ am[i] = -3.4e38f; al[i] = 0.f; }
}

// ---------- one-time weight packing ----------
// W34 [128][1024] = [Wx3 | flipRows(Wx4)], b34 [1024]
// W2p [l][tid 512][128]: scan2 per-thread weights; tid=(s<<7)|q, widx=m*32+kk
//      -> Wh34[(32s+kk)*512 + (4q+m)]
// W1p [l][tid 512][64]:  scan1 per-thread weights; tid=(s<<6)|q;
//      w<32: c=w>>3,k=w&7 -> Wh12[(s*8+k)*256 + 4q+c]
//      w>=32 (s<2 only): c,r -> Wx12[(s*8+r) row, flipped for l=1]
// b12 [l][256]
__global__ __launch_bounds__(256) void k_pack(
        const float* __restrict__ Wx1, const float* __restrict__ Wh1, const float* __restrict__ b1,
        const float* __restrict__ Wx2, const float* __restrict__ Wh2, const float* __restrict__ b2,
        const float* __restrict__ Wx3, const float* __restrict__ Wh3, const float* __restrict__ b3,
        const float* __restrict__ Wx4, const float* __restrict__ Wh4, const float* __restrict__ b4,
        float* __restrict__ W34, float* __restrict__ b34, float* __restrict__ W2p,
        float* __restrict__ W1p, float* __restrict__ b12){
    int i0 = blockIdx.x * 256 + threadIdx.x;
    int stride = gridDim.x * 256;
    for (int e = i0; e < 131072; e += stride){
        int k = e >> 10, n = e & 1023;
        W34[e] = (n < 512) ? Wx3[k*512 + n] : Wx4[(127 - k)*512 + (n - 512)];
    }
    for (int e = i0; e < 1024; e += stride) b34[e] = (e < 512) ? b3[e] : b4[e - 512];
    for (int e = i0; e < 131072; e += stride){
        int l = e >> 16, r = e & 65535, tid = r >> 7, widx = r & 127;
        int q = tid & 127, s = tid >> 7;
        int m = widx >> 5, kk = widx & 31;
        W2p[e] = (l ? Wh4 : Wh3)[(32*s + kk)*512 + (4*q + m)];
    }
    for (int e = i0; e < 65536; e += stride){
        int l = e >> 15, r = e & 32767, tid = r >> 6, wq = r & 63;
        int q = tid & 63, s = tid >> 6;
        float v = 0.f;
        if (wq < 32){
            int c = wq >> 3, k = wq & 7;
            v = (l ? Wh2 : Wh1)[(s*8 + k)*256 + (4*q + c)];
        } else if (s < 2){
            int c = (wq - 32) >> 3, rr = (wq - 32) & 7;
            int rg = s*8 + rr, col = 4*q + c;
            v = l ? Wx2[(15 - rg)*256 + col] : Wx1[rg*256 + col];
        }
        W1p[e] = v;
    }
    for (int e = i0; e < 512; e += stride) b12[e] = (e < 256) ? b1[e] : b2[e - 256];
}

// ---------- conv1d chunk: rows [t0, t0+C) -> xcv[(b*C+trel)][16]
__global__ __launch_bounds__(256) void k_conv(const float* __restrict__ X,
        const float* __restrict__ W, const float* __restrict__ Bv,
        float* __restrict__ out, int t0, int lc){
    __shared__ float Ws[512];
    __shared__ float bs[16];
    int tid = threadIdx.x;
    Ws[tid] = W[tid]; Ws[tid + 256] = W[tid + 256];
    if (tid < 16) bs[tid] = Bv[tid];
    __syncthreads();
    int m = blockIdx.x * 256 + tid;               // b*C + trel
    int b = m >> lc, trel = m & ((1 << lc) - 1);
    int t = t0 + trel;
    float o[16];
    #pragma unroll
    for (int co = 0; co < 16; ++co) o[co] = bs[co];
    #pragma unroll
    for (int w = 0; w < 4; ++w){
        int tt = t + w - 1;
        if (tt >= 0 && tt < TFULL){
            const float* xr = X + ((size_t)(b << 12) + tt) * 8;
            #pragma unroll
            for (int ci = 0; ci < 8; ++ci){
                float v = xr[ci];
                #pragma unroll
                for (int co = 0; co < 16; ++co) o[co] += v * Ws[(w*8 + ci)*16 + co];
            }
        }
    }
    float* op = out + (size_t)m * 16;
    #pragma unroll
    for (int q = 0; q < 4; ++q)
        *(float4*)(op + q*4) = make_float4(o[q*4], o[q*4+1], o[q*4+2], o[q*4+3]);
}

// ---------- layer-1 scan chunk: LSTM1 (l=0) / LSTM2 (l=1, row-flipped Wx).
// One WG per (lstm, batch); 512 threads = (col-quad q 0..63, slice s 0..7).
// slice s: h[8s..8s+8); s<2 additionally x rows [8s..8s+8).
__global__ void
__attribute__((amdgpu_flat_work_group_size(512, 512), amdgpu_waves_per_eu(2, 2)))
k_scan1(const float* __restrict__ x, const float* __restrict__ W1p,
        const float* __restrict__ b12,
        float* __restrict__ cc, float* __restrict__ st1, int C){
    int l = blockIdx.x >> 5;
    int b = blockIdx.x & 31;
    int tid = threadIdx.x;
    int q = tid & 63;
    int s = tid >> 6;
    float4 w[16];
    {
        const float4* wp = (const float4*)(W1p + ((size_t)l*512 + tid)*64);
        #pragma unroll
        for (int i = 0; i < 16; ++i) w[i] = wp[i];
        #pragma unroll
        for (int i = 0; i < 16; ++i) PIN4(w[i]);
    }
    float bi0 = 0.f, bi1 = 0.f, bi2 = 0.f, bi3 = 0.f;
    if (tid < 64){
        bi0 = b12[l*256 + tid];       bi1 = b12[l*256 + 64 + tid];
        bi2 = b12[l*256 + 128 + tid]; bi3 = b12[l*256 + 192 + tid];
    }

    __shared__ float xs[128 * 16];   // up-to-128-step input tile
    __shared__ float zp[8 * 256];    // [s][col]
    __shared__ float hbufs[64];
    float c = 0.f;
    int sidx = (l*32 + b)*64 + (tid & 63);
    if (tid < 64){ c = st1[sidx]; hbufs[tid] = st1[4096 + sidx]; }
    __syncthreads();

    const float* xb = x + ((size_t)b * C) * 16;
    float* ccb = cc + ((size_t)b * C) * 128 + (l << 6);

    for (int t = 0; t < C; ++t){
        int st = t & 127;
        if (st == 0){
            __syncthreads();
            const float4* src = (const float4*)(xb + (size_t)t * 16);
            float4* dst = (float4*)xs;
            if (t + (tid >> 2) < C) dst[tid] = src[tid];
            __syncthreads();
        }
        float a0 = 0.f, a1 = 0.f, a2 = 0.f, a3 = 0.f;
        const float4* hb4 = (const float4*)hbufs + (s << 1);
        #pragma unroll
        for (int k4 = 0; k4 < 2; ++k4){
            float4 hv = hb4[k4];
            a0 = fmaf(hv.x, w[k4].x, a0);     a0 = fmaf(hv.y, w[k4].y, a0);
            a0 = fmaf(hv.z, w[k4].z, a0);     a0 = fmaf(hv.w, w[k4].w, a0);
            a1 = fmaf(hv.x, w[2+k4].x, a1);   a1 = fmaf(hv.y, w[2+k4].y, a1);
            a1 = fmaf(hv.z, w[2+k4].z, a1);   a1 = fmaf(hv.w, w[2+k4].w, a1);
            a2 = fmaf(hv.x, w[4+k4].x, a2);   a2 = fmaf(hv.y, w[4+k4].y, a2);
            a2 = fmaf(hv.z, w[4+k4].z, a2);   a2 = fmaf(hv.w, w[4+k4].w, a2);
            a3 = fmaf(hv.x, w[6+k4].x, a3);   a3 = fmaf(hv.y, w[6+k4].y, a3);
            a3 = fmaf(hv.z, w[6+k4].z, a3);   a3 = fmaf(hv.w, w[6+k4].w, a3);
        }
        if (s < 2){   // wave-uniform: x contribution
            const float4* xr = (const float4*)(xs + st * 16) + (s << 1);
            #pragma unroll
            for (int r4 = 0; r4 < 2; ++r4){
                float4 xv = xr[r4];
                a0 = fmaf(xv.x, w[8+r4].x, a0);    a0 = fmaf(xv.y, w[8+r4].y, a0);
                a0 = fmaf(xv.z, w[8+r4].z, a0);    a0 = fmaf(xv.w, w[8+r4].w, a0);
                a1 = fmaf(xv.x, w[10+r4].x, a1);   a1 = fmaf(xv.y, w[10+r4].y, a1);
                a1 = fmaf(xv.z, w[10+r4].z, a1);   a1 = fmaf(xv.w, w[10+r4].w, a1);
                a2 = fmaf(xv.x, w[12+r4].x, a2);   a2 = fmaf(xv.y, w[12+r4].y, a2);
                a2 = fmaf(xv.z, w[12+r4].z, a2);   a2 = fmaf(xv.w, w[12+r4].w, a2);
                a3 = fmaf(xv.x, w[14+r4].x, a3);   a3 = fmaf(xv.y, w[14+r4].y, a3);
                a3 = fmaf(xv.z, w[14+r4].z, a3);   a3 = fmaf(xv.w, w[14+r4].w, a3);
            }
        }
        *(float4*)(zp + (s << 8) + (q << 2)) = make_float4(a0, a1, a2, a3);
        __syncthreads();
        if (tid < 64){
            float zi = bi0, zf = bi1, zg = bi2, zo = bi3;
            #pragma unroll
            for (int ss = 0; ss < 8; ++ss){
                const float* zr = zp + (ss << 8);
                zi += zr[tid]; zf += zr[64 + tid]; zg += zr[128 + tid]; zo += zr[192 + tid];
            }
            c = sigf(zf) * c + sigf(zi) * tanh_(zg);
            float h = sigf(zo) * tanh_(c);
            hbufs[tid] = h;
            ccb[(size_t)t * 128 + tid] = h;
        }
        __syncthreads();
    }
    if (tid < 64){ st1[sidx] = c; st1[4096 + sidx] = hbufs[tid]; }
}

// ---------- GEMM: C[M][ldc] = op(A @ B + bias). BM=128, BN=64, BK=64.
// 128 threads, 8x8 micro. LDS pads (129/68) keep bank aliasing <=2-way (free).
template<bool TANH>
__global__ __launch_bounds__(128) void k_gemm(
        const float* __restrict__ A, int lda,
        const float* __restrict__ B, int ldb,
        const float* __restrict__ bias,
        float* __restrict__ Cm, int ldc, int K){
    __shared__ float As[64 * 129];   // transposed: As[k][r]
    __shared__ float Bs[64 * 68];    // Bs[k][n]
    int tid = threadIdx.x;
    int tx = tid & 7;
    int ty = tid >> 3;
    int r0 = blockIdx.x * 128;
    int n0 = blockIdx.y * 64;
    float acc[8][8];
    #pragma unroll
    for (int i = 0; i < 8; ++i)
        #pragma unroll
        for (int n = 0; n < 8; ++n) acc[i][n] = 0.f;

    for (int kb = 0; kb < K; kb += 64){
        __syncthreads();
        for (int idx = tid; idx < 2048; idx += 128){
            int r = idx >> 4, k4 = idx & 15;
            float4 v = *(const float4*)(A + (size_t)(r0 + r) * lda + kb + k4*4);
            As[(k4*4 + 0)*129 + r] = v.x;
            As[(k4*4 + 1)*129 + r] = v.y;
            As[(k4*4 + 2)*129 + r] = v.z;
            As[(k4*4 + 3)*129 + r] = v.w;
        }
        for (int idx = tid; idx < 1024; idx += 128){
            int n4 = idx & 15, k = idx >> 4;
            float4 v = *(const float4*)(B + (size_t)(kb + k) * ldb + n0 + n4*4);
            *(float4*)(Bs + k*68 + n4*4) = v;
        }
        __syncthreads();
        #pragma unroll 4
        for (int k = 0; k < 64; ++k){
            float a[8];
            #pragma unroll
            for (int i = 0; i < 8; ++i) a[i] = As[k*129 + ty*8 + i];
            float4 b0 = *(const float4*)(Bs + k*68 + tx*8);
            float4 b1 = *(const float4*)(Bs + k*68 + tx*8 + 4);
            float bq[8] = {b0.x, b0.y, b0.z, b0.w, b1.x, b1.y, b1.z, b1.w};
            #pragma unroll
            for (int i = 0; i < 8; ++i)
                #pragma unroll
                for (int n = 0; n < 8; ++n) acc[i][n] += a[i] * bq[n];
        }
    }
    #pragma unroll
    for (int i = 0; i < 8; ++i){
        size_t rr = (size_t)r0 + ty*8 + i;
        float* cp = Cm + rr * ldc + n0 + tx*8;
        float ov[8];
        #pragma unroll
        for (int n = 0; n < 8; ++n){
            float v = acc[i][n] + bias[n0 + tx*8 + n];
            ov[n] = TANH ? tanh_(v) : v;
        }
        *(float4*)cp       = make_float4(ov[0], ov[1], ov[2], ov[3]);
        *(float4*)(cp + 4) = make_float4(ov[4], ov[5], ov[6], ov[7]);
    }
}

// ---------- layer-2 scan chunk (LSTM3 l=0 / LSTM4 l=1), state in st2.
// One WG per (lstm, batch); 512 threads = (col-quad q 0..127, slice s 0..3).
// Thread: 4 cols x 32 k; 128 weights in VGPRs (budget 256 at 2 waves/EU).
__global__ void
__attribute__((amdgpu_flat_work_group_size(512, 512), amdgpu_waves_per_eu(2, 2)))
k_scan2(const float* __restrict__ xg, const float* __restrict__ W2p,
        float* __restrict__ enc, float* __restrict__ st2, int C){
    int l = blockIdx.x >> 5;
    int b = blockIdx.x & 31;
    int tid = threadIdx.x;
    int q = tid & 127;
    int s = tid >> 7;
    float4 w[32];    // w[m*8 + kk4]: col m (0..3), k-quad kk4 (0..7) in slice s
    {
        const float4* wp = (const float4*)(W2p + ((size_t)l*512 + tid)*128);
        #pragma unroll
        for (int i = 0; i < 32; ++i) w[i] = wp[i];
        #pragma unroll
        for (int i = 0; i < 32; ++i) PIN4(w[i]);
    }

    __shared__ float zp[4 * 512];    // [s][col]
    __shared__ float hbufs[128];
    float c = 0.f;
    int sidx = (l*32 + b)*128 + (tid & 127);
    if (tid < 128){ c = st2[sidx]; hbufs[tid] = st2[8192 + sidx]; }
    __syncthreads();

    const float4* xp4 = (const float4*)(xg + ((size_t)b * C) * 1024 + (l << 9)) + q;
    float* encb = enc + ((size_t)b * C) * 256 + (l << 7);

    float4 xn = make_float4(0.f, 0.f, 0.f, 0.f);
    if (s == 0) xn = xp4[0];
    for (int t = 0; t < C; ++t){
        float a0, a1, a2, a3;
        if (s == 0){   // wave-uniform: xg (incl. bias) + prefetch next step
            a0 = xn.x; a1 = xn.y; a2 = xn.z; a3 = xn.w;
            int tn = (t + 1 < C) ? t + 1 : t;
            xn = xp4[(size_t)tn * 256];
        } else { a0 = a1 = a2 = a3 = 0.f; }
        const float4* hb4 = (const float4*)hbufs + (s << 3);
        #pragma unroll
        for (int k4 = 0; k4 < 8; ++k4){
            float4 hv = hb4[k4];
            a0 = fmaf(hv.x, w[k4].x, a0);      a0 = fmaf(hv.y, w[k4].y, a0);
            a0 = fmaf(hv.z, w[k4].z, a0);      a0 = fmaf(hv.w, w[k4].w, a0);
            a1 = fmaf(hv.x, w[8+k4].x, a1);    a1 = fmaf(hv.y, w[8+k4].y, a1);
            a1 = fmaf(hv.z, w[8+k4].z, a1);    a1 = fmaf(hv.w, w[8+k4].w, a1);
            a2 = fmaf(hv.x, w[16+k4].x, a2);   a2 = fmaf(hv.y, w[16+k4].y, a2);
            a2 = fmaf(hv.z, w[16+k4].z, a2);   a2 = fmaf(hv.w, w[16+k4].w, a2);
            a3 = fmaf(hv.x, w[24+k4].x, a3);   a3 = fmaf(hv.y, w[24+k4].y, a3);
            a3 = fmaf(hv.z, w[24+k4].z, a3);   a3 = fmaf(hv.w, w[24+k4].w, a3);
        }
        *(float4*)(zp + (s << 9) + (q << 2)) = make_float4(a0, a1, a2, a3);
        __syncthreads();
        if (tid < 128){
            float zi = zp[tid]       + zp[512 + tid]  + zp[1024 + tid] + zp[1536 + tid];
            float zf = zp[128 + tid] + zp[640 + tid]  + zp[1152 + tid] + zp[1664 + tid];
            float zg = zp[256 + tid] + zp[768 + tid]  + zp[1280 + tid] + zp[1792 + tid];
            float zo = zp[384 + tid] + zp[896 + tid]  + zp[1408 + tid] + zp[1920 + tid];
            c = sigf(zf) * c + sigf(zi) * tanh_(zg);
            float h = sigf(zo) * tanh_(c);
            hbufs[tid] = h;
            encb[(size_t)t * 256 + tid] = h;
        }
        __syncthreads();
    }
    if (tid < 128){ st2[sidx] = c; st2[8192 + sidx] = hbufs[tid]; }
}

// ---------- score = u @ Va + bva  (u = tanh(enc@Wa+ba) from GEMM<true>)
__global__ __launch_bounds__(256) void k_scorev(const float* __restrict__ u,
        const float* __restrict__ Va, const float* __restrict__ bva,
        float* __restrict__ sc){
    int m = blockIdx.x * 256 + threadIdx.x;
    const float4* up = (const float4*)(u + (size_t)m * 64);
    const float4* vp = (const float4*)Va;
    float acc = 0.f;
    #pragma unroll
    for (int i = 0; i < 16; ++i){
        float4 v = up[i], w = vp[i];
        acc += v.x*w.x + v.y*w.y + v.z*w.z + v.w*w.w;
    }
    sc[m] = acc + bva[0];
}

// ---------- online-softmax attention accumulate over one chunk.
// Per batch b: m,l,acc[256] updated flash-style. 1 WG/b, 1024 threads,
// t-range split 4-way (thread = (feature 0..255, slice 0..3)).
__global__ __launch_bounds__(1024) void k_attn(const float* __restrict__ sc,
        const float* __restrict__ enc, float* __restrict__ am,
        float* __restrict__ al, float* __restrict__ acc, int C){
    int b = blockIdx.x, tid = threadIdx.x;
    __shared__ float es[1024];
    __shared__ float red[16];
    __shared__ float sh[2];
    const float* sp = sc + (size_t)b * C;
    float mloc = -3.4e38f;
    for (int t = tid; t < C; t += 1024) mloc = fmaxf(mloc, sp[t]);
    #pragma unroll
    for (int off = 32; off; off >>= 1) mloc = fmaxf(mloc, __shfl_down(mloc, off));
    if ((tid & 63) == 0) red[tid >> 6] = mloc;
    __syncthreads();
    if (tid == 0){
        float mc = -3.4e38f;
        #pragma unroll
        for (int i = 0; i < 16; ++i) mc = fmaxf(mc, red[i]);
        float mo = am[b];
        float mn = fmaxf(mo, mc);
        sh[0] = mn;
        sh[1] = fexp2(1.44269504f * (mo - mn));   // alpha (0 on first chunk)
        am[b] = mn;
    }
    __syncthreads();
    float mn = sh[0], alpha = sh[1];
    float eloc = 0.f;
    for (int t = tid; t < C; t += 1024){
        float e = fexp2(1.44269504f * (sp[t] - mn));
        es[t] = e; eloc += e;
    }
    #pragma unroll
    for (int off = 32; off; off >>= 1) eloc += __shfl_down(eloc, off);
    if ((tid & 63) == 0) red[tid >> 6] = eloc;
    __syncthreads();
    if (tid == 0){
        float sm = 0.f;
        #pragma unroll
        for (int i = 0; i < 16; ++i) sm += red[i];
        al[b] = al[b] * alpha + sm;
    }
    // partial acc over slice sl of the t-range (es[] ready: barrier above)
    int jf = tid & 255, sl = tid >> 8;
    int tlen = C >> 2;
    const float* ep = enc + ((size_t)b * C + (size_t)sl * tlen) * 256 + jf;
    const float* eb = es + sl * tlen;
    float a = 0.f;
    for (int t = 0; t < tlen; ++t) a = fmaf(eb[t], ep[(size_t)t * 256], a);
    __syncthreads();
    es[tid] = a;
    __syncthreads();
    if (tid < 256)
        acc[b*256 + tid] = acc[b*256 + tid] * alpha
                         + ((es[tid] + es[256 + tid]) + (es[512 + tid] + es[768 + tid]));
}

// ---------- head: ctx = acc/l, h1 = tanh(ctx@Wd1+bd1), out = h1@Wd2+bd2
__global__ __launch_bounds__(256) void k_head(const float* __restrict__ acc,
        const float* __restrict__ al,
        const float* __restrict__ Wd1, const float* __restrict__ bd1,
        const float* __restrict__ Wd2, const float* __restrict__ bd2,
        float* __restrict__ out){
    __shared__ float ctxs[32 * 256];
    __shared__ float h1s[32 * 64];
    int tid = threadIdx.x;
    for (int idx = tid; idx < 8192; idx += 256){
        int b = idx >> 8;
        ctxs[idx] = acc[idx] / al[b];
    }
    __syncthreads();
    for (int idx = tid; idx < 2048; idx += 256){
        int b = idx >> 6, n = idx & 63;
        float a = bd1[n];
        for (int i = 0; i < 256; ++i) a += ctxs[b*256 + i] * Wd1[i*64 + n];
        h1s[idx] = tanh_(a);
    }
    __syncthreads();
    if (tid < 32){
        float a = bd2[0];
        #pragma unroll
        for (int n = 0; n < 64; ++n) a += h1s[tid*64 + n] * Wd2[n];
        out[tid] = a;
    }
}

// ============================================================================
extern "C" void kernel_launch(void* const* d_in, const int* in_sizes, int n_in,
                              void* d_out, int out_size, void* d_ws, size_t ws_size,
                              hipStream_t stream){
    const float* X     = (const float*)d_in[0];
    const float* convw = (const float*)d_in[1];
    const float* convb = (const float*)d_in[2];
    const float* Wx1 = (const float*)d_in[3];
    const float* Wh1 = (const float*)d_in[4];
    const float* b1  = (const float*)d_in[5];
    const float* Wx2 = (const float*)d_in[6];
    const float* Wh2 = (const float*)d_in[7];
    const float* b2  = (const float*)d_in[8];
    const float* Wx3 = (const float*)d_in[9];
    const float* Wh3 = (const float*)d_in[10];
    const float* b3  = (const float*)d_in[11];
    const float* Wx4 = (const float*)d_in[12];
    const float* Wh4 = (const float*)d_in[13];
    const float* b4  = (const float*)d_in[14];
    const float* Wa  = (const float*)d_in[15];
    const float* ba  = (const float*)d_in[16];
    const float* Va  = (const float*)d_in[17];
    const float* bva = (const float*)d_in[18];
    const float* Wd1 = (const float*)d_in[19];
    const float* bd1 = (const float*)d_in[20];
    const float* Wd2 = (const float*)d_in[21];
    const float* bd2 = (const float*)d_in[22];
    float* out = (float*)d_out;
    (void)in_sizes; (void)n_in; (void)out_size;

    // ---- choose chunk size C so everything fits in ws_size ----
    const size_t fixedFl = 131072 + 1024 + 131072 + 65536 + 512
                         + 8192 + 16384 + 32 + 32 + 8192 + 32*1024;
    size_t capFl = ws_size / 4;
    int C = 1024;
    while (C > 32){
        size_t need = fixedFl + (size_t)NB * C * (16 + 128 + 1024 + 256 + 64);
        if (need <= capFl) break;
        C >>= 1;
    }
    int lc = 31 - __builtin_clz((unsigned)C);
    int nch = TFULL / C;

    float* ws   = (float*)d_ws;
    float* W34  = ws;                      // 131072
    float* b34  = W34 + 131072;            // 1024
    float* W2p  = b34 + 1024;              // 131072
    float* W1p  = W2p + 131072;            // 65536
    float* b12  = W1p + 65536;             // 512
    float* st1  = b12 + 512;               // 8192  (c | h)
    float* st2  = st1 + 8192;              // 16384 (c | h)
    float* am   = st2 + 16384;             // 32
    float* al   = am + 32;                 // 32
    float* acc  = al + 32;                 // 8192
    float* scb  = acc + 8192;              // 32*1024
    float* xcv  = scb + 32*1024;           // 32*C*16
    float* ccb  = xcv + (size_t)NB*C*16;   // 32*C*128
    float* xgb  = ccb + (size_t)NB*C*128;  // 32*C*1024
    float* enb  = xgb + (size_t)NB*C*1024; // 32*C*256
    float* ub   = enb + (size_t)NB*C*256;  // 32*C*64

    k_init<<<64, 256, 0, stream>>>(st1, st2, am, al, acc);
    k_pack<<<512, 256, 0, stream>>>(Wx1, Wh1, b1, Wx2, Wh2, b2,
                                    Wx3, Wh3, b3, Wx4, Wh4, b4,
                                    W34, b34, W2p, W1p, b12);

    for (int ch = 0; ch < nch; ++ch){
        int t0 = ch * C;
        k_conv<<<NB*C/256, 256, 0, stream>>>(X, convw, convb, xcv, t0, lc);
        k_scan1<<<64, 512, 0, stream>>>(xcv, W1p, b12, ccb, st1, C);
        // xg = cc @ W34 + b34 : M=32*C, K=128, N=1024
        k_gemm<false><<<dim3(NB*C/128, 16), 128, 0, stream>>>(
            ccb, 128, W34, 1024, b34, xgb, 1024, 128);
        k_scan2<<<64, 512, 0, stream>>>(xgb, W2p, enb, st2, C);
        // u = tanh(enc @ Wa + ba) : M=32*C, K=256, N=64
        k_gemm<true><<<dim3(NB*C/128, 1), 128, 0, stream>>>(
            enb, 256, Wa, 64, ba, ub, 64, 256);
        k_scorev<<<NB*C/256, 256, 0, stream>>>(ub, Va, bva, scb);
        k_attn<<<32, 1024, 0, stream>>>(scb, enb, am, al, acc, C);
    }
    k_head<<<1, 256, 0, stream>>>(acc, al, Wd1, bd1, Wd2, bd2, out);
}